// Round 7
// baseline (214.315 us; speedup 1.0000x reference)
//
#include <hip/hip_runtime.h>

// GCN 2-layer. g = (X@W1)*dinv[row] (bf16); h = relu(dinv*(sum g[src]+g[self])+b1);
// g2 = (h@W2)*dinv; out = dinv*(sum g2[src]+g2[self])+b2.
// Build: 2-level counting sort by dst -> CSR (6 dispatches total).
// gemm1: bf16 MFMA hi/lo 3-pass (f32-accurate), zero LDS, W as global B-frags.
// aggfuse: agg128 gather + in-LDS h tile + fused W2 MFMA -> g2 (no h buffer).
// agg64: 16B/lane bf16 gathers of g2.

constexpr int IN_CH = 128;
constexpr int HID_CH = 128;
constexpr int OUT_CH = 64;
constexpr int BSH = 8;        // 256 nodes per bucket
constexpr int CAP = 6144;     // per-bucket edge capacity (mean 4092, sigma ~64)

typedef __attribute__((ext_vector_type(8))) short bf16x8;
typedef __attribute__((ext_vector_type(4))) float f32x4;

__device__ __forceinline__ unsigned short f2bf(float f) {   // RNE
    unsigned int x = __float_as_uint(f);
    return (unsigned short)((x + 0x7fffu + ((x >> 16) & 1u)) >> 16);
}
__device__ __forceinline__ float bf2f(unsigned short h) {
    return __uint_as_float(((unsigned int)h) << 16);
}

// ---------------- graph build ----------------
// packed pair: src (bits 0..19) | (dst & 255) << 20

__global__ __launch_bounds__(256) void bucketA_kernel(
        const int* __restrict__ ei, int E, int nbuck,
        int* __restrict__ gcnt, int* __restrict__ pairs) {
    __shared__ int hist[1024];
    __shared__ int base[1024];
    int tid = threadIdx.x;
    for (int i = tid; i < nbuck; i += 256) hist[i] = 0;
    __syncthreads();
    int lo = (int)((long long)blockIdx.x * E / gridDim.x);
    int hi = (int)((long long)(blockIdx.x + 1) * E / gridDim.x);
    for (int e = lo + tid; e < hi; e += 256)
        atomicAdd(&hist[ei[E + e] >> BSH], 1);
    __syncthreads();
    for (int i = tid; i < nbuck; i += 256) {
        int c = hist[i];
        base[i] = (c > 0) ? atomicAdd(&gcnt[i], c) : 0;
        hist[i] = 0;
    }
    __syncthreads();
    for (int e = lo + tid; e < hi; e += 256) {
        int s = ei[e];
        int d = ei[E + e];
        int b = d >> BSH;
        int off = base[b] + atomicAdd(&hist[b], 1);
        if (off < CAP) pairs[(size_t)b * CAP + off] = s | ((d & 255) << 20);
    }
}

__global__ __launch_bounds__(256) void bucketB_kernel(
        const int* __restrict__ pairs, const int* __restrict__ gcnt, int nbuck, int n,
        int2* __restrict__ rsdeg, float* __restrict__ dinv, int* __restrict__ csr) {
    __shared__ int cnt[256];
    __shared__ int scan[256];
    __shared__ int cur[256];
    __shared__ int ssum[256];
    int b = blockIdx.x, tid = threadIdx.x;
    int node0 = b << BSH;
    int m = min(gcnt[b], CAP);
    const int* p = pairs + (size_t)b * CAP;

    // inline exclusive bucket prefix: bs = sum(gcnt[0..b))
    int partial = 0;
    for (int i = tid; i < b; i += 256) partial += gcnt[i];
    ssum[tid] = partial;
    cnt[tid] = 0;
    __syncthreads();
    for (int s = 128; s > 0; s >>= 1) {
        if (tid < s) ssum[tid] += ssum[tid + s];
        __syncthreads();
    }
    int bs = ssum[0];

    for (int i = tid; i < m; i += 256) atomicAdd(&cnt[(p[i] >> 20) & 255], 1);
    __syncthreads();
    int v = cnt[tid];
    scan[tid] = v;
    __syncthreads();
    for (int s = 1; s < 256; s <<= 1) {
        int t = (tid >= s) ? scan[tid - s] : 0;
        __syncthreads();
        scan[tid] += t;
        __syncthreads();
    }
    int excl = scan[tid] - v;
    int node = node0 + tid;
    if (node < n) {
        rsdeg[node] = make_int2(bs + excl, v);
        dinv[node] = rsqrtf((float)(v + 1));   // +1 self loop
    }
    cnt[tid] = excl;
    cur[tid] = 0;
    __syncthreads();
    for (int i = tid; i < m; i += 256) {
        int pk = p[i];
        int dl = (pk >> 20) & 255;
        int pos = bs + cnt[dl] + atomicAdd(&cur[dl], 1);
        csr[pos] = pk & 0xFFFFF;
    }
}

// ---------------- W -> B-fragment pre-pass (+ gcnt zero in block 2) ----------------
// B-frag for mfma_f32_16x16x32_bf16: lane l holds B[k=ks*32+(l>>4)*8+j][col=nt*16+(l&15)].
// Storage: frag f = nt*4+ks; wf[(f*2+hl)*512 + l*8 + j], hl: 0=hi,1=lo.

__global__ void wfrag_kernel(const float* __restrict__ W1, const float* __restrict__ W2,
                             unsigned short* __restrict__ wf1, unsigned short* __restrict__ wf2,
                             int* __restrict__ gcnt, int nbuck) {
    if (blockIdx.x == 2) {
        for (int i = threadIdx.x; i < nbuck; i += 256) gcnt[i] = 0;
        return;
    }
    const float* W = blockIdx.x ? W2 : W1;
    unsigned short* wf = blockIdx.x ? wf2 : wf1;
    int cols = blockIdx.x ? OUT_CH : HID_CH;
    int nfrag = (cols / 16) * 4;
    for (int slot = threadIdx.x; slot < nfrag * 64; slot += 256) {
        int f = slot >> 6;
        int l = slot & 63;
        int nt = f >> 2, ks = f & 3;
        int col = nt * 16 + (l & 15);
        int k0 = ks * 32 + (l >> 4) * 8;
        unsigned short* dhi = wf + ((size_t)f * 2 + 0) * 512 + l * 8;
        unsigned short* dlo = wf + ((size_t)f * 2 + 1) * 512 + l * 8;
        #pragma unroll
        for (int j = 0; j < 8; ++j) {
            float v = W[(size_t)(k0 + j) * cols + col];
            unsigned short h = f2bf(v);
            dhi[j] = h;
            dlo[j] = f2bf(v - bf2f(h));
        }
    }
}

// ---------------- GEMM 1: f32 A (hi/lo, 3-pass), zero LDS ----------------

template<int NT>
__global__ __launch_bounds__(256) void gemm_mfma_kernel(
        const float* __restrict__ X, const unsigned short* __restrict__ wf,
        const float* __restrict__ dinv, unsigned short* __restrict__ G, int n) {
    int wid = threadIdx.x >> 6;
    int lane = threadIdx.x & 63;
    int rowBase = blockIdx.x * 128 + wid * 32;
    int mn = lane & 15;
    int kg = lane >> 4;

    bf16x8 ahi[2][4], alo[2][4];
    #pragma unroll
    for (int mt = 0; mt < 2; ++mt) {
        int row = min(rowBase + mt * 16 + mn, n - 1);
        const float* xr = X + (size_t)row * 128;
        #pragma unroll
        for (int ks = 0; ks < 4; ++ks) {
            int k0 = ks * 32 + kg * 8;
            float4 a = *(const float4*)&xr[k0];
            float4 b = *(const float4*)&xr[k0 + 4];
            float v[8] = {a.x, a.y, a.z, a.w, b.x, b.y, b.z, b.w};
            bf16x8 h, l;
            #pragma unroll
            for (int j = 0; j < 8; ++j) {
                unsigned short hh = f2bf(v[j]);
                h[j] = (short)hh;
                l[j] = (short)f2bf(v[j] - bf2f(hh));
            }
            ahi[mt][ks] = h;
            alo[mt][ks] = l;
        }
    }

    f32x4 acc[2][NT];
    #pragma unroll
    for (int mt = 0; mt < 2; ++mt)
        #pragma unroll
        for (int t = 0; t < NT; ++t)
            acc[mt][t] = (f32x4){0.f, 0.f, 0.f, 0.f};

    const bf16x8* wfv = (const bf16x8*)wf;
    #pragma unroll
    for (int nt = 0; nt < NT; ++nt) {
        #pragma unroll
        for (int ks = 0; ks < 4; ++ks) {
            int f = nt * 4 + ks;
            bf16x8 bhi = wfv[(size_t)(f * 2 + 0) * 64 + lane];
            bf16x8 blo = wfv[(size_t)(f * 2 + 1) * 64 + lane];
            acc[0][nt] = __builtin_amdgcn_mfma_f32_16x16x32_bf16(ahi[0][ks], bhi, acc[0][nt], 0, 0, 0);
            acc[1][nt] = __builtin_amdgcn_mfma_f32_16x16x32_bf16(ahi[1][ks], bhi, acc[1][nt], 0, 0, 0);
            acc[0][nt] = __builtin_amdgcn_mfma_f32_16x16x32_bf16(alo[0][ks], bhi, acc[0][nt], 0, 0, 0);
            acc[1][nt] = __builtin_amdgcn_mfma_f32_16x16x32_bf16(alo[1][ks], bhi, acc[1][nt], 0, 0, 0);
            acc[0][nt] = __builtin_amdgcn_mfma_f32_16x16x32_bf16(ahi[0][ks], blo, acc[0][nt], 0, 0, 0);
            acc[1][nt] = __builtin_amdgcn_mfma_f32_16x16x32_bf16(ahi[1][ks], blo, acc[1][nt], 0, 0, 0);
        }
    }

    #pragma unroll
    for (int mt = 0; mt < 2; ++mt) {
        #pragma unroll
        for (int r = 0; r < 4; ++r) {
            int row = rowBase + mt * 16 + kg * 4 + r;
            if (row < n) {
                float dv = dinv[row];
                #pragma unroll
                for (int nt = 0; nt < NT; ++nt)
                    G[(size_t)row * (NT * 16) + nt * 16 + mn] = f2bf(acc[mt][nt][r] * dv);
            }
        }
    }
}

// ---------------- fused agg128 + gemm2 ----------------
// 1024 thr = 16 waves = 16 nodes. Per wave: gather-aggregate one node's g rows
// (4 groups x 16 lanes, chunked quarters), shfl-reduce, h-row (bf16, relu) to LDS.
// Then waves 0..3 compute h_tile(16x128) @ W2(128x64) via MFMA (2-pass hi/lo),
// scale by dinv[row], store g2 bf16. LDS chunk-XOR swizzle -> 2-way conflicts.

__device__ __forceinline__ void acc_bf16x8(uint4 u, float* a) {
    a[0] += __uint_as_float(u.x << 16);
    a[1] += __uint_as_float(u.x & 0xffff0000u);
    a[2] += __uint_as_float(u.y << 16);
    a[3] += __uint_as_float(u.y & 0xffff0000u);
    a[4] += __uint_as_float(u.z << 16);
    a[5] += __uint_as_float(u.z & 0xffff0000u);
    a[6] += __uint_as_float(u.w << 16);
    a[7] += __uint_as_float(u.w & 0xffff0000u);
}

__global__ __launch_bounds__(1024) void aggfuse_kernel(
        const unsigned short* __restrict__ g, const int* __restrict__ csr,
        const int2* __restrict__ rsdeg, const float* __restrict__ dinv,
        const float* __restrict__ bias, const unsigned short* __restrict__ wf2,
        unsigned short* __restrict__ G2, int n) {
    __shared__ unsigned short hs[16][128];   // 4 KB h tile, chunk-swizzled
    int wid = threadIdx.x >> 6;              // 0..15 = row in tile
    int lane = threadIdx.x & 63;
    int w = blockIdx.x * 16 + wid;
    int grp = lane >> 4;                     // 0..3
    int cl = lane & 15;                      // 16B chunk
    bool valid = (w < n);
    int wc = valid ? w : (n - 1);

    const uint4* base = (const uint4*)g;     // row stride = 16 uint4
    float a[8] = {0.f, 0.f, 0.f, 0.f, 0.f, 0.f, 0.f, 0.f};
    int2 rd = rsdeg[wc];
    int start = rd.x, cnt = rd.y;
    if (grp == 0)
        acc_bf16x8(base[(size_t)wc * 16 + cl], a);   // self loop
    int j = (cnt * grp) >> 2;
    int jend = (cnt * (grp + 1)) >> 2;
    for (; j + 3 < jend; j += 4) {
        int s0 = csr[start + j];
        int s1 = csr[start + j + 1];
        int s2 = csr[start + j + 2];
        int s3 = csr[start + j + 3];
        uint4 u0 = base[(size_t)s0 * 16 + cl];
        uint4 u1 = base[(size_t)s1 * 16 + cl];
        uint4 u2 = base[(size_t)s2 * 16 + cl];
        uint4 u3 = base[(size_t)s3 * 16 + cl];
        acc_bf16x8(u0, a);
        acc_bf16x8(u1, a);
        acc_bf16x8(u2, a);
        acc_bf16x8(u3, a);
    }
    for (; j < jend; ++j)
        acc_bf16x8(base[(size_t)csr[start + j] * 16 + cl], a);
    #pragma unroll
    for (int i = 0; i < 8; ++i) {
        a[i] += __shfl_xor(a[i], 16);
        a[i] += __shfl_xor(a[i], 32);
    }
    if (grp == 0) {
        float dv = dinv[wc];
        float4 b0 = ((const float4*)bias)[cl * 2];
        float4 b1 = ((const float4*)bias)[cl * 2 + 1];
        float o[8];
        o[0] = fmaxf(fmaf(dv, a[0], b0.x), 0.f);
        o[1] = fmaxf(fmaf(dv, a[1], b0.y), 0.f);
        o[2] = fmaxf(fmaf(dv, a[2], b0.z), 0.f);
        o[3] = fmaxf(fmaf(dv, a[3], b0.w), 0.f);
        o[4] = fmaxf(fmaf(dv, a[4], b1.x), 0.f);
        o[5] = fmaxf(fmaf(dv, a[5], b1.y), 0.f);
        o[6] = fmaxf(fmaf(dv, a[6], b1.z), 0.f);
        o[7] = fmaxf(fmaf(dv, a[7], b1.w), 0.f);
        uint4 pk;
        pk.x = valid ? ((unsigned int)f2bf(o[0]) | ((unsigned int)f2bf(o[1]) << 16)) : 0u;
        pk.y = valid ? ((unsigned int)f2bf(o[2]) | ((unsigned int)f2bf(o[3]) << 16)) : 0u;
        pk.z = valid ? ((unsigned int)f2bf(o[4]) | ((unsigned int)f2bf(o[5]) << 16)) : 0u;
        pk.w = valid ? ((unsigned int)f2bf(o[6]) | ((unsigned int)f2bf(o[7]) << 16)) : 0u;
        *(uint4*)&hs[wid][(cl ^ (wid & 7)) << 3] = pk;   // chunk-XOR swizzle
    }
    __syncthreads();

    // MFMA phase: wave nt = wid (0..3); A row = mn = cl, k-group = grp
    if (wid < 4) {
        int nt = wid;
        int mn = cl, kg = grp;
        bf16x8 af[4];
        #pragma unroll
        for (int ks = 0; ks < 4; ++ks)
            af[ks] = *(const bf16x8*)&hs[mn][(((ks << 2) | kg) ^ (mn & 7)) << 3];
        f32x4 acc = (f32x4){0.f, 0.f, 0.f, 0.f};
        const bf16x8* wfv = (const bf16x8*)wf2;
        #pragma unroll
        for (int ks = 0; ks < 4; ++ks) {
            int f = nt * 4 + ks;
            bf16x8 bhi = wfv[(size_t)(f * 2 + 0) * 64 + lane];
            bf16x8 blo = wfv[(size_t)(f * 2 + 1) * 64 + lane];
            acc = __builtin_amdgcn_mfma_f32_16x16x32_bf16(af[ks], bhi, acc, 0, 0, 0);
            acc = __builtin_amdgcn_mfma_f32_16x16x32_bf16(af[ks], blo, acc, 0, 0, 0);
        }
        #pragma unroll
        for (int r = 0; r < 4; ++r) {
            int row = blockIdx.x * 16 + kg * 4 + r;
            if (row < n)
                G2[(size_t)row * 64 + nt * 16 + mn] = f2bf(acc[r] * dinv[row]);
        }
    }
}

// ---------------- agg64: 16B/lane bf16 gathers of g2 ----------------

__global__ void agg64_kernel(const unsigned short* __restrict__ g, const int* __restrict__ csr,
                             const int2* __restrict__ rsdeg,
                             const float* __restrict__ dinv, const float* __restrict__ bias,
                             float* __restrict__ out, int n) {
    int w = (int)((blockIdx.x * blockDim.x + threadIdx.x) >> 6);
    int lane = threadIdx.x & 63;
    if (w >= n) return;
    int grp = lane >> 3;        // 0..7
    int cl = lane & 7;          // 16B chunk
    const uint4* base = (const uint4*)g;    // row stride = 8 uint4
    float a[8] = {0.f, 0.f, 0.f, 0.f, 0.f, 0.f, 0.f, 0.f};
    int2 rd = rsdeg[w];
    int start = rd.x, cnt = rd.y;
    if (grp == 0)
        acc_bf16x8(base[(size_t)w * 8 + cl], a);
    int j = (cnt * grp) >> 3;
    int jend = (cnt * (grp + 1)) >> 3;
    for (; j + 1 < jend; j += 2) {
        int s0 = csr[start + j];
        int s1 = csr[start + j + 1];
        uint4 u0 = base[(size_t)s0 * 8 + cl];
        uint4 u1 = base[(size_t)s1 * 8 + cl];
        acc_bf16x8(u0, a);
        acc_bf16x8(u1, a);
    }
    for (; j < jend; ++j)
        acc_bf16x8(base[(size_t)csr[start + j] * 8 + cl], a);
    #pragma unroll
    for (int i = 0; i < 8; ++i) {
        a[i] += __shfl_xor(a[i], 8);
        a[i] += __shfl_xor(a[i], 16);
        a[i] += __shfl_xor(a[i], 32);
    }
    if (grp == 0) {
        float dv = dinv[w];
        float4 b0 = ((const float4*)bias)[cl * 2];
        float4 b1 = ((const float4*)bias)[cl * 2 + 1];
        float4 o0, o1;
        o0.x = fmaf(dv, a[0], b0.x);
        o0.y = fmaf(dv, a[1], b0.y);
        o0.z = fmaf(dv, a[2], b0.z);
        o0.w = fmaf(dv, a[3], b0.w);
        o1.x = fmaf(dv, a[4], b1.x);
        o1.y = fmaf(dv, a[5], b1.y);
        o1.z = fmaf(dv, a[6], b1.z);
        o1.w = fmaf(dv, a[7], b1.w);
        ((float4*)out)[(size_t)w * 16 + cl * 2] = o0;
        ((float4*)out)[(size_t)w * 16 + cl * 2 + 1] = o1;
    }
}

// ---------------- launch ----------------

extern "C" void kernel_launch(void* const* d_in, const int* in_sizes, int n_in,
                              void* d_out, int out_size, void* d_ws, size_t ws_size,
                              hipStream_t stream) {
    const float* x  = (const float*)d_in[0];
    const int*   ei = (const int*)d_in[1];
    const float* W1 = (const float*)d_in[2];
    const float* b1 = (const float*)d_in[3];
    const float* W2 = (const float*)d_in[4];
    const float* b2 = (const float*)d_in[5];
    float* out = (float*)d_out;

    int n = in_sizes[0] / IN_CH;
    int E = in_sizes[1] / 2;
    int nbuck = (n + 255) >> BSH;
    if (nbuck > 1024 || n >= (1 << 20)) return;

    char* ws = (char*)d_ws;
    size_t offG    = 0;                                 // g bf16 (n*128*2)
    size_t offG2   = offG + (size_t)n * 128 * 2;        // g2 bf16 (n*64*2)
    size_t offDinv = offG2 + (size_t)n * 64 * 2;        // dinv f32
    size_t offRS   = offDinv + (size_t)n * 4;           // rsdeg int2
    size_t offGC   = offRS + (size_t)n * 8;             // gcnt
    size_t offCsr  = offGC + 4096;                      // csr (E int)
    size_t offWF1  = offCsr + (size_t)E * 4;            // 64 KB
    size_t offWF2  = offWF1 + 32 * 2 * 512 * 2;         // 32 KB
    size_t offPair = offWF2 + 16 * 2 * 512 * 2;         // pairs (nbuck*CAP*4)
    size_t need = offPair + (size_t)nbuck * CAP * 4;
    if (ws_size < need) return;

    unsigned short* g   = (unsigned short*)(ws + offG);
    unsigned short* g2  = (unsigned short*)(ws + offG2);
    float* dinv         = (float*)(ws + offDinv);
    int2*  rsdeg        = (int2*)(ws + offRS);
    int*   gcnt         = (int*)(ws + offGC);
    int*   csr          = (int*)(ws + offCsr);
    unsigned short* wf1 = (unsigned short*)(ws + offWF1);
    unsigned short* wf2 = (unsigned short*)(ws + offWF2);
    int*   pairs        = (int*)(ws + offPair);

    wfrag_kernel<<<3, 256, 0, stream>>>(W1, W2, wf1, wf2, gcnt, nbuck);
    bucketA_kernel<<<512, 256, 0, stream>>>(ei, E, nbuck, gcnt, pairs);
    bucketB_kernel<<<nbuck, 256, 0, stream>>>(pairs, gcnt, nbuck, n, rsdeg, dinv, csr);

    gemm_mfma_kernel<8><<<(n + 127) / 128, 256, 0, stream>>>(x, wf1, dinv, g, n);
    aggfuse_kernel<<<(n + 15) / 16, 1024, 0, stream>>>(g, csr, rsdeg, dinv, b1, wf2, g2, n);
    agg64_kernel<<<(n + 3) / 4, 256, 0, stream>>>(g2, csr, rsdeg, dinv, b2, out, n);
}

// Round 8
// 194.215 us; speedup vs baseline: 1.1035x; 1.1035x over previous
//
#include <hip/hip_runtime.h>

// GCN 2-layer. g_raw = X@W1 (bf16, unscaled); h = relu(dinv*(sum dinv[s]*g_raw[s] +
// dinv[w]*g_raw[w]) + b1) (bf16); g2 = (h@W2)*dinv; out = dinv*(sum g2[s]+g2[w]) + b2.
// Build: 2-level counting sort by dst -> CSR. Merged dispatch: bucketA (blocks 0..511)
// runs CONCURRENTLY with gemm1 (no dinv dep since scaling moved into agg128).
// GEMMs: bf16 MFMA hi/lo split (f32-accurate), zero LDS, W as global B-frags.
// Agg: 16B/lane bf16 gathers, chunked groups, small blocks (round-6 proven form).

constexpr int IN_CH = 128;
constexpr int HID_CH = 128;
constexpr int OUT_CH = 64;
constexpr int BSH = 8;        // 256 nodes per bucket
constexpr int CAP = 6144;     // per-bucket edge capacity (mean 4092, sigma ~64)
constexpr int NBA = 512;      // bucketA blocks inside merged dispatch

typedef __attribute__((ext_vector_type(8))) short bf16x8;
typedef __attribute__((ext_vector_type(4))) float f32x4;

__device__ __forceinline__ unsigned short f2bf(float f) {   // RNE
    unsigned int x = __float_as_uint(f);
    return (unsigned short)((x + 0x7fffu + ((x >> 16) & 1u)) >> 16);
}
__device__ __forceinline__ float bf2f(unsigned short h) {
    return __uint_as_float(((unsigned int)h) << 16);
}

// ---------------- W -> B-fragment pre-pass (+ gcnt zero in block 2) ----------------
// B-frag for mfma_f32_16x16x32_bf16: lane l holds B[k=ks*32+(l>>4)*8+j][col=nt*16+(l&15)].
// Storage: frag f = nt*4+ks; wf[(f*2+hl)*512 + l*8 + j], hl: 0=hi,1=lo.

__global__ void wfrag_kernel(const float* __restrict__ W1, const float* __restrict__ W2,
                             unsigned short* __restrict__ wf1, unsigned short* __restrict__ wf2,
                             int* __restrict__ gcnt, int nbuck) {
    if (blockIdx.x == 2) {
        for (int i = threadIdx.x; i < nbuck; i += 256) gcnt[i] = 0;
        return;
    }
    const float* W = blockIdx.x ? W2 : W1;
    unsigned short* wf = blockIdx.x ? wf2 : wf1;
    int cols = blockIdx.x ? OUT_CH : HID_CH;
    int nfrag = (cols / 16) * 4;
    for (int slot = threadIdx.x; slot < nfrag * 64; slot += 256) {
        int f = slot >> 6;
        int l = slot & 63;
        int nt = f >> 2, ks = f & 3;
        int col = nt * 16 + (l & 15);
        int k0 = ks * 32 + (l >> 4) * 8;
        unsigned short* dhi = wf + ((size_t)f * 2 + 0) * 512 + l * 8;
        unsigned short* dlo = wf + ((size_t)f * 2 + 1) * 512 + l * 8;
        #pragma unroll
        for (int j = 0; j < 8; ++j) {
            float v = W[(size_t)(k0 + j) * cols + col];
            unsigned short h = f2bf(v);
            dhi[j] = h;
            dlo[j] = f2bf(v - bf2f(h));
        }
    }
}

// ---------------- merged: bucketA (blocks 0..NBA-1) || gemm1 (rest) ----------------
// packed pair: src (bits 0..19) | (dst & 255) << 20

__global__ __launch_bounds__(256) void merged_kernel(
        const int* __restrict__ ei, int E, int nbuck,
        int* __restrict__ gcnt, int* __restrict__ pairs,
        const float* __restrict__ X, const unsigned short* __restrict__ wf,
        unsigned short* __restrict__ G, int n) {
    __shared__ int hist[1024];
    __shared__ int base[1024];
    int tid = threadIdx.x;

    if (blockIdx.x < NBA) {
        // ---- bucketA ----
        int bid = blockIdx.x;
        for (int i = tid; i < nbuck; i += 256) hist[i] = 0;
        __syncthreads();
        int lo = (int)((long long)bid * E / NBA);
        int hi = (int)((long long)(bid + 1) * E / NBA);
        for (int e = lo + tid; e < hi; e += 256)
            atomicAdd(&hist[ei[E + e] >> BSH], 1);
        __syncthreads();
        for (int i = tid; i < nbuck; i += 256) {
            int c = hist[i];
            base[i] = (c > 0) ? atomicAdd(&gcnt[i], c) : 0;
            hist[i] = 0;
        }
        __syncthreads();
        for (int e = lo + tid; e < hi; e += 256) {
            int s = ei[e];
            int d = ei[E + e];
            int b = d >> BSH;
            int off = base[b] + atomicAdd(&hist[b], 1);
            if (off < CAP) pairs[(size_t)b * CAP + off] = s | ((d & 255) << 20);
        }
        return;
    }

    // ---- gemm1: f32 A (hi/lo, 3-pass), zero LDS, NO dinv scale ----
    constexpr int NT = 8;
    int blk = blockIdx.x - NBA;
    int wid = tid >> 6;
    int lane = tid & 63;
    int rowBase = blk * 128 + wid * 32;
    int mn = lane & 15;
    int kg = lane >> 4;

    bf16x8 ahi[2][4], alo[2][4];
    #pragma unroll
    for (int mt = 0; mt < 2; ++mt) {
        int row = min(rowBase + mt * 16 + mn, n - 1);
        const float* xr = X + (size_t)row * 128;
        #pragma unroll
        for (int ks = 0; ks < 4; ++ks) {
            int k0 = ks * 32 + kg * 8;
            float4 a = *(const float4*)&xr[k0];
            float4 b = *(const float4*)&xr[k0 + 4];
            float v[8] = {a.x, a.y, a.z, a.w, b.x, b.y, b.z, b.w};
            bf16x8 h, l;
            #pragma unroll
            for (int j = 0; j < 8; ++j) {
                unsigned short hh = f2bf(v[j]);
                h[j] = (short)hh;
                l[j] = (short)f2bf(v[j] - bf2f(hh));
            }
            ahi[mt][ks] = h;
            alo[mt][ks] = l;
        }
    }

    f32x4 acc[2][NT];
    #pragma unroll
    for (int mt = 0; mt < 2; ++mt)
        #pragma unroll
        for (int t = 0; t < NT; ++t)
            acc[mt][t] = (f32x4){0.f, 0.f, 0.f, 0.f};

    const bf16x8* wfv = (const bf16x8*)wf;
    #pragma unroll
    for (int nt = 0; nt < NT; ++nt) {
        #pragma unroll
        for (int ks = 0; ks < 4; ++ks) {
            int f = nt * 4 + ks;
            bf16x8 bhi = wfv[(size_t)(f * 2 + 0) * 64 + lane];
            bf16x8 blo = wfv[(size_t)(f * 2 + 1) * 64 + lane];
            acc[0][nt] = __builtin_amdgcn_mfma_f32_16x16x32_bf16(ahi[0][ks], bhi, acc[0][nt], 0, 0, 0);
            acc[1][nt] = __builtin_amdgcn_mfma_f32_16x16x32_bf16(ahi[1][ks], bhi, acc[1][nt], 0, 0, 0);
            acc[0][nt] = __builtin_amdgcn_mfma_f32_16x16x32_bf16(alo[0][ks], bhi, acc[0][nt], 0, 0, 0);
            acc[1][nt] = __builtin_amdgcn_mfma_f32_16x16x32_bf16(alo[1][ks], bhi, acc[1][nt], 0, 0, 0);
            acc[0][nt] = __builtin_amdgcn_mfma_f32_16x16x32_bf16(ahi[0][ks], blo, acc[0][nt], 0, 0, 0);
            acc[1][nt] = __builtin_amdgcn_mfma_f32_16x16x32_bf16(ahi[1][ks], blo, acc[1][nt], 0, 0, 0);
        }
    }

    #pragma unroll
    for (int mt = 0; mt < 2; ++mt) {
        #pragma unroll
        for (int r = 0; r < 4; ++r) {
            int row = rowBase + mt * 16 + kg * 4 + r;
            if (row < n) {
                #pragma unroll
                for (int nt = 0; nt < NT; ++nt)
                    G[(size_t)row * (NT * 16) + nt * 16 + mn] = f2bf(acc[mt][nt][r]);
            }
        }
    }
}

// ---------------- bucketB: per-node count/scan/scatter + rsdeg + dinv ----------------

__global__ __launch_bounds__(256) void bucketB_kernel(
        const int* __restrict__ pairs, const int* __restrict__ gcnt, int nbuck, int n,
        int2* __restrict__ rsdeg, float* __restrict__ dinv, int* __restrict__ csr) {
    __shared__ int cnt[256];
    __shared__ int scan[256];
    __shared__ int cur[256];
    __shared__ int ssum[256];
    int b = blockIdx.x, tid = threadIdx.x;
    int node0 = b << BSH;
    int m = min(gcnt[b], CAP);
    const int* p = pairs + (size_t)b * CAP;

    int partial = 0;
    for (int i = tid; i < b; i += 256) partial += gcnt[i];
    ssum[tid] = partial;
    cnt[tid] = 0;
    __syncthreads();
    for (int s = 128; s > 0; s >>= 1) {
        if (tid < s) ssum[tid] += ssum[tid + s];
        __syncthreads();
    }
    int bs = ssum[0];

    for (int i = tid; i < m; i += 256) atomicAdd(&cnt[(p[i] >> 20) & 255], 1);
    __syncthreads();
    int v = cnt[tid];
    scan[tid] = v;
    __syncthreads();
    for (int s = 1; s < 256; s <<= 1) {
        int t = (tid >= s) ? scan[tid - s] : 0;
        __syncthreads();
        scan[tid] += t;
        __syncthreads();
    }
    int excl = scan[tid] - v;
    int node = node0 + tid;
    if (node < n) {
        rsdeg[node] = make_int2(bs + excl, v);
        dinv[node] = rsqrtf((float)(v + 1));   // +1 self loop
    }
    cnt[tid] = excl;
    cur[tid] = 0;
    __syncthreads();
    for (int i = tid; i < m; i += 256) {
        int pk = p[i];
        int dl = (pk >> 20) & 255;
        int pos = bs + cnt[dl] + atomicAdd(&cur[dl], 1);
        csr[pos] = pk & 0xFFFFF;
    }
}

// ---------------- aggregation helpers ----------------

__device__ __forceinline__ void acc_bf16x8(uint4 u, float* a) {
    a[0] += __uint_as_float(u.x << 16);
    a[1] += __uint_as_float(u.x & 0xffff0000u);
    a[2] += __uint_as_float(u.y << 16);
    a[3] += __uint_as_float(u.y & 0xffff0000u);
    a[4] += __uint_as_float(u.z << 16);
    a[5] += __uint_as_float(u.z & 0xffff0000u);
    a[6] += __uint_as_float(u.w << 16);
    a[7] += __uint_as_float(u.w & 0xffff0000u);
}

__device__ __forceinline__ void fma_bf16x8(uint4 u, float s, float* a) {
    a[0] = fmaf(s, __uint_as_float(u.x << 16), a[0]);
    a[1] = fmaf(s, __uint_as_float(u.x & 0xffff0000u), a[1]);
    a[2] = fmaf(s, __uint_as_float(u.y << 16), a[2]);
    a[3] = fmaf(s, __uint_as_float(u.y & 0xffff0000u), a[3]);
    a[4] = fmaf(s, __uint_as_float(u.z << 16), a[4]);
    a[5] = fmaf(s, __uint_as_float(u.z & 0xffff0000u), a[5]);
    a[6] = fmaf(s, __uint_as_float(u.w << 16), a[6]);
    a[7] = fmaf(s, __uint_as_float(u.w & 0xffff0000u), a[7]);
}

// layer 1: 256B raw rows; wave = 4 groups x 16 lanes; per-row dinv[src] fma;
// output h bf16 (+bias, relu). Round-6 structure (proven 64 us).
__global__ void agg128_kernel(const unsigned short* __restrict__ g, const int* __restrict__ csr,
                              const int2* __restrict__ rsdeg,
                              const float* __restrict__ dinv, const float* __restrict__ bias,
                              unsigned short* __restrict__ h, int n) {
    int w = (int)((blockIdx.x * blockDim.x + threadIdx.x) >> 6);
    int lane = threadIdx.x & 63;
    if (w >= n) return;
    int grp = lane >> 4;        // 0..3
    int cl = lane & 15;         // 16B chunk (channels cl*8 .. cl*8+7)
    const uint4* base = (const uint4*)g;    // row stride = 16 uint4
    float a[8] = {0.f, 0.f, 0.f, 0.f, 0.f, 0.f, 0.f, 0.f};
    int2 rd = rsdeg[w];
    int start = rd.x, cnt = rd.y;
    float dv = dinv[w];
    if (grp == 0)
        fma_bf16x8(base[(size_t)w * 16 + cl], dv, a);   // self loop: dinv[w]*g_raw[w]
    int j = (cnt * grp) >> 2;
    int jend = (cnt * (grp + 1)) >> 2;
    for (; j + 3 < jend; j += 4) {
        int s0 = csr[start + j];
        int s1 = csr[start + j + 1];
        int s2 = csr[start + j + 2];
        int s3 = csr[start + j + 3];
        uint4 u0 = base[(size_t)s0 * 16 + cl];
        uint4 u1 = base[(size_t)s1 * 16 + cl];
        uint4 u2 = base[(size_t)s2 * 16 + cl];
        uint4 u3 = base[(size_t)s3 * 16 + cl];
        float d0 = dinv[s0], d1 = dinv[s1], d2 = dinv[s2], d3 = dinv[s3];
        fma_bf16x8(u0, d0, a);
        fma_bf16x8(u1, d1, a);
        fma_bf16x8(u2, d2, a);
        fma_bf16x8(u3, d3, a);
    }
    for (; j < jend; ++j) {
        int s = csr[start + j];
        fma_bf16x8(base[(size_t)s * 16 + cl], dinv[s], a);
    }
    #pragma unroll
    for (int i = 0; i < 8; ++i) {
        a[i] += __shfl_xor(a[i], 16);
        a[i] += __shfl_xor(a[i], 32);
    }
    if (grp == 0) {
        float4 b0 = ((const float4*)bias)[cl * 2];
        float4 b1 = ((const float4*)bias)[cl * 2 + 1];
        float o[8];
        o[0] = fmaxf(fmaf(dv, a[0], b0.x), 0.f);
        o[1] = fmaxf(fmaf(dv, a[1], b0.y), 0.f);
        o[2] = fmaxf(fmaf(dv, a[2], b0.z), 0.f);
        o[3] = fmaxf(fmaf(dv, a[3], b0.w), 0.f);
        o[4] = fmaxf(fmaf(dv, a[4], b1.x), 0.f);
        o[5] = fmaxf(fmaf(dv, a[5], b1.y), 0.f);
        o[6] = fmaxf(fmaf(dv, a[6], b1.z), 0.f);
        o[7] = fmaxf(fmaf(dv, a[7], b1.w), 0.f);
        uint4 pk;
        pk.x = (unsigned int)f2bf(o[0]) | ((unsigned int)f2bf(o[1]) << 16);
        pk.y = (unsigned int)f2bf(o[2]) | ((unsigned int)f2bf(o[3]) << 16);
        pk.z = (unsigned int)f2bf(o[4]) | ((unsigned int)f2bf(o[5]) << 16);
        pk.w = (unsigned int)f2bf(o[6]) | ((unsigned int)f2bf(o[7]) << 16);
        ((uint4*)h)[(size_t)w * 16 + cl] = pk;
    }
}

// ---------------- GEMM 2: bf16 A (exact), 2-pass, dinv scale on output ----------------

template<int NT>
__global__ __launch_bounds__(256) void gemm_mfma_bf16A_kernel(
        const unsigned short* __restrict__ X, const unsigned short* __restrict__ wf,
        const float* __restrict__ dinv, unsigned short* __restrict__ G, int n) {
    int wid = threadIdx.x >> 6;
    int lane = threadIdx.x & 63;
    int rowBase = blockIdx.x * 128 + wid * 32;
    int mn = lane & 15;
    int kg = lane >> 4;

    bf16x8 a[2][4];
    #pragma unroll
    for (int mt = 0; mt < 2; ++mt) {
        int row = min(rowBase + mt * 16 + mn, n - 1);
        const unsigned short* xr = X + (size_t)row * 128;
        #pragma unroll
        for (int ks = 0; ks < 4; ++ks)
            a[mt][ks] = *(const bf16x8*)&xr[ks * 32 + kg * 8];
    }

    f32x4 acc[2][NT];
    #pragma unroll
    for (int mt = 0; mt < 2; ++mt)
        #pragma unroll
        for (int t = 0; t < NT; ++t)
            acc[mt][t] = (f32x4){0.f, 0.f, 0.f, 0.f};

    const bf16x8* wfv = (const bf16x8*)wf;
    #pragma unroll
    for (int nt = 0; nt < NT; ++nt) {
        #pragma unroll
        for (int ks = 0; ks < 4; ++ks) {
            int f = nt * 4 + ks;
            bf16x8 bhi = wfv[(size_t)(f * 2 + 0) * 64 + lane];
            bf16x8 blo = wfv[(size_t)(f * 2 + 1) * 64 + lane];
            acc[0][nt] = __builtin_amdgcn_mfma_f32_16x16x32_bf16(a[0][ks], bhi, acc[0][nt], 0, 0, 0);
            acc[1][nt] = __builtin_amdgcn_mfma_f32_16x16x32_bf16(a[1][ks], bhi, acc[1][nt], 0, 0, 0);
            acc[0][nt] = __builtin_amdgcn_mfma_f32_16x16x32_bf16(a[0][ks], blo, acc[0][nt], 0, 0, 0);
            acc[1][nt] = __builtin_amdgcn_mfma_f32_16x16x32_bf16(a[1][ks], blo, acc[1][nt], 0, 0, 0);
        }
    }

    #pragma unroll
    for (int mt = 0; mt < 2; ++mt) {
        #pragma unroll
        for (int r = 0; r < 4; ++r) {
            int row = rowBase + mt * 16 + kg * 4 + r;
            if (row < n) {
                float dv = dinv[row];
                #pragma unroll
                for (int nt = 0; nt < NT; ++nt)
                    G[(size_t)row * (NT * 16) + nt * 16 + mn] = f2bf(acc[mt][nt][r] * dv);
            }
        }
    }
}

// ---------------- agg64: 16B/lane bf16 gathers of g2 (pre-scaled) ----------------

__global__ void agg64_kernel(const unsigned short* __restrict__ g, const int* __restrict__ csr,
                             const int2* __restrict__ rsdeg,
                             const float* __restrict__ dinv, const float* __restrict__ bias,
                             float* __restrict__ out, int n) {
    int w = (int)((blockIdx.x * blockDim.x + threadIdx.x) >> 6);
    int lane = threadIdx.x & 63;
    if (w >= n) return;
    int grp = lane >> 3;        // 0..7
    int cl = lane & 7;          // 16B chunk
    const uint4* base = (const uint4*)g;    // row stride = 8 uint4
    float a[8] = {0.f, 0.f, 0.f, 0.f, 0.f, 0.f, 0.f, 0.f};
    int2 rd = rsdeg[w];
    int start = rd.x, cnt = rd.y;
    if (grp == 0)
        acc_bf16x8(base[(size_t)w * 8 + cl], a);
    int j = (cnt * grp) >> 3;
    int jend = (cnt * (grp + 1)) >> 3;
    for (; j + 1 < jend; j += 2) {
        int s0 = csr[start + j];
        int s1 = csr[start + j + 1];
        uint4 u0 = base[(size_t)s0 * 8 + cl];
        uint4 u1 = base[(size_t)s1 * 8 + cl];
        acc_bf16x8(u0, a);
        acc_bf16x8(u1, a);
    }
    for (; j < jend; ++j)
        acc_bf16x8(base[(size_t)csr[start + j] * 8 + cl], a);
    #pragma unroll
    for (int i = 0; i < 8; ++i) {
        a[i] += __shfl_xor(a[i], 8);
        a[i] += __shfl_xor(a[i], 16);
        a[i] += __shfl_xor(a[i], 32);
    }
    if (grp == 0) {
        float dv = dinv[w];
        float4 b0 = ((const float4*)bias)[cl * 2];
        float4 b1 = ((const float4*)bias)[cl * 2 + 1];
        float4 o0, o1;
        o0.x = fmaf(dv, a[0], b0.x);
        o0.y = fmaf(dv, a[1], b0.y);
        o0.z = fmaf(dv, a[2], b0.z);
        o0.w = fmaf(dv, a[3], b0.w);
        o1.x = fmaf(dv, a[4], b1.x);
        o1.y = fmaf(dv, a[5], b1.y);
        o1.z = fmaf(dv, a[6], b1.z);
        o1.w = fmaf(dv, a[7], b1.w);
        ((float4*)out)[(size_t)w * 16 + cl * 2] = o0;
        ((float4*)out)[(size_t)w * 16 + cl * 2 + 1] = o1;
    }
}

// ---------------- launch ----------------

extern "C" void kernel_launch(void* const* d_in, const int* in_sizes, int n_in,
                              void* d_out, int out_size, void* d_ws, size_t ws_size,
                              hipStream_t stream) {
    const float* x  = (const float*)d_in[0];
    const int*   ei = (const int*)d_in[1];
    const float* W1 = (const float*)d_in[2];
    const float* b1 = (const float*)d_in[3];
    const float* W2 = (const float*)d_in[4];
    const float* b2 = (const float*)d_in[5];
    float* out = (float*)d_out;

    int n = in_sizes[0] / IN_CH;
    int E = in_sizes[1] / 2;
    int nbuck = (n + 255) >> BSH;
    if (nbuck > 1024 || n >= (1 << 20)) return;

    char* ws = (char*)d_ws;
    size_t offG    = 0;                                 // g_raw bf16 (n*128*2)
    size_t offH    = offG + (size_t)n * 128 * 2;        // h bf16 (n*128*2); pairs overlaps
    size_t offG2   = offH + (size_t)n * 128 * 2;        // g2 bf16 (n*64*2)
    size_t offDinv = offG2 + (size_t)n * 64 * 2;
    size_t offRS   = offDinv + (size_t)n * 4;           // rsdeg int2
    size_t offGC   = offRS + (size_t)n * 8;             // gcnt
    size_t offCsr  = offGC + 4096;                      // csr (E int)
    size_t offWF1  = offCsr + (size_t)E * 4;            // 64 KB
    size_t offWF2  = offWF1 + 32 * 2 * 512 * 2;         // 32 KB
    size_t need = offWF2 + 16 * 2 * 512 * 2;
    if (ws_size < need) return;
    // pairs (nbuck*CAP*4 = 96 B/node) overlaps h (256 B/node): pairs dead after bucketB,
    // h first written by agg128 (later). Safe.

    unsigned short* g   = (unsigned short*)(ws + offG);
    unsigned short* h   = (unsigned short*)(ws + offH);
    int*   pairs        = (int*)(ws + offH);
    unsigned short* g2  = (unsigned short*)(ws + offG2);
    float* dinv         = (float*)(ws + offDinv);
    int2*  rsdeg        = (int2*)(ws + offRS);
    int*   gcnt         = (int*)(ws + offGC);
    int*   csr          = (int*)(ws + offCsr);
    unsigned short* wf1 = (unsigned short*)(ws + offWF1);
    unsigned short* wf2 = (unsigned short*)(ws + offWF2);

    int gemmGrid = (n + 127) / 128;

    wfrag_kernel<<<3, 256, 0, stream>>>(W1, W2, wf1, wf2, gcnt, nbuck);
    merged_kernel<<<NBA + gemmGrid, 256, 0, stream>>>(ei, E, nbuck, gcnt, pairs, x, wf1, g, n);
    bucketB_kernel<<<nbuck, 256, 0, stream>>>(pairs, gcnt, nbuck, n, rsdeg, dinv, csr);

    agg128_kernel<<<(n + 3) / 4, 256, 0, stream>>>(g, csr, rsdeg, dinv, b1, h, n);
    gemm_mfma_bf16A_kernel<4><<<gemmGrid, 256, 0, stream>>>(h, wf2, dinv, g2, n);
    agg64_kernel<<<(n + 3) / 4, 256, 0, stream>>>(g2, csr, rsdeg, dinv, b2, out, n);
}